// Round 9
// baseline (173.736 us; speedup 1.0000x reference)
//
#include <hip/hip_runtime.h>
#include <hip/hip_bf16.h>

typedef float f32x4  __attribute__((ext_vector_type(4)));
typedef float f32x16 __attribute__((ext_vector_type(16)));
typedef short s16x8  __attribute__((ext_vector_type(8)));

#define NB 4
#define NC 128
#define NNPOS 4096
#define KSP 8          // block-level key split
#define LOG2E 1.44269504088896f

__device__ __forceinline__ short bf16s(float x) {
    __hip_bfloat16 h = __float2bfloat16(x);
    return *reinterpret_cast<short*>(&h);
}
__device__ __forceinline__ int packbf2(float lo, float hi) {
    __hip_bfloat162 t = __float22bfloat162_rn(float2{lo, hi});
    return *reinterpret_cast<int*>(&t);
}
__device__ __forceinline__ float bf2f(unsigned short u) {
    unsigned int v = ((unsigned int)u) << 16;
    return *reinterpret_cast<float*>(&v);
}
__device__ __forceinline__ float exp2fast(float x) {
    return __builtin_amdgcn_exp2f(x);   // native v_exp_f32 (base 2)
}

// ------------------------------------------------------------------
// Kernel 1: QKV projection via bf16 MFMA 16x16x32 (unchanged from R8).
// qb/kb: [b][n][16] bf16 (q pre-scaled by log2e so attn uses exp2).
// vt: PV-B-frag tile order [b][key/16][c/32][c%32][slot],
//     slot = swap-bits-2,3 of (key%16)  -> score C/D regs == PV A-frag
//     order in attn (no cross-lane ops).
// ------------------------------------------------------------------
__global__ __launch_bounds__(256) void qkv_kernel(
    const float* __restrict__ x,
    const float* __restrict__ wq, const float* __restrict__ bq,
    const float* __restrict__ wk, const float* __restrict__ bk,
    const float* __restrict__ wv, const float* __restrict__ bv,
    short* __restrict__ qb, short* __restrict__ kb, short* __restrict__ vt)
{
    const int n0  = blockIdx.x * 32;
    const int b   = blockIdx.y;
    const int tid = threadIdx.x;
    const int w = tid >> 6, lane = tid & 63, quad = lane >> 4, nn = lane & 15;

    __shared__ __align__(16) short xsT[32 * 136];

    #pragma unroll
    for (int p = 0; p < 4; ++p) {
        int idx = tid + p * 256;
        int cc = idx >> 3, n4 = (idx & 7) * 4;
        f32x4 xv = *(const f32x4*)&x[((size_t)(b * NC + cc)) * NNPOS + n0 + n4];
        #pragma unroll
        for (int j = 0; j < 4; ++j)
            xsT[(n4 + j) * 136 + cc] = bf16s(xv[j]);
    }

    s16x8 af[3][4];
    bool  live[3];
    f32x4 biasv[3];
    #pragma unroll
    for (int t = 0; t < 3; ++t) {
        int rid = 3 * w + t;
        int R   = rid * 16;
        const float* wsrc = nullptr; const float* bsrc = nullptr; int row0 = 0;
        float scale = 1.0f;
        if (rid < 8)        { wsrc = wv; bsrc = bv; row0 = R; }
        else if (rid == 8)  { wsrc = wq; bsrc = bq; row0 = 0; scale = LOG2E; }
        else if (rid == 10) { wsrc = wk; bsrc = bk; row0 = 0; }
        live[t] = (wsrc != nullptr);
        #pragma unroll
        for (int r = 0; r < 4; ++r)
            biasv[t][r] = live[t] ? scale * bsrc[row0 + quad * 4 + r] : 0.0f;
        if (live[t]) {
            #pragma unroll
            for (int ks = 0; ks < 4; ++ks) {
                const float* src = wsrc + (size_t)(row0 + nn) * NC + ks * 32 + quad * 8;
                f32x4 wa = *(const f32x4*)src;
                f32x4 wb = *(const f32x4*)(src + 4);
                s16x8 f;
                #pragma unroll
                for (int j = 0; j < 4; ++j) {
                    f[j]     = bf16s(scale * wa[j]);
                    f[j + 4] = bf16s(scale * wb[j]);
                }
                af[t][ks] = f;
            }
        }
    }
    __syncthreads();

    f32x4 acc[3][2];
    #pragma unroll
    for (int t = 0; t < 3; ++t)
        #pragma unroll
        for (int nt = 0; nt < 2; ++nt)
            acc[t][nt] = biasv[t];

    #pragma unroll
    for (int nt = 0; nt < 2; ++nt) {
        s16x8 bf[4];
        #pragma unroll
        for (int ks = 0; ks < 4; ++ks)
            bf[ks] = *(const s16x8*)&xsT[(nt * 16 + nn) * 136 + ks * 32 + quad * 8];
        #pragma unroll
        for (int t = 0; t < 3; ++t)
            if (live[t])
                #pragma unroll
                for (int ks = 0; ks < 4; ++ks)
                    acc[t][nt] = __builtin_amdgcn_mfma_f32_16x16x32_bf16(af[t][ks], bf[ks], acc[t][nt], 0, 0, 0);
    }

    // V-slot key permutation: swap bits 2<->3 of (key%16)
    const int slot = (nn & 3) | ((nn & 4) << 1) | ((nn & 8) >> 1);

    #pragma unroll
    for (int t = 0; t < 3; ++t) {
        if (!live[t]) continue;
        int R = (3 * w + t) * 16;
        #pragma unroll
        for (int nt = 0; nt < 2; ++nt) {
            int n = n0 + nt * 16 + nn;
            int kg = (n0 + nt * 16) >> 4;
            #pragma unroll
            for (int r = 0; r < 4; ++r) {
                short v = bf16s(acc[t][nt][r]);
                int row = R + quad * 4 + r;      // quad-uniform branch
                if (row < 128) {
                    int ct = row >> 5, c31r = row & 31;
                    vt[((((size_t)b * 256 + kg) * 4 + ct) * 32 + c31r) * 16 + slot] = v;
                } else if (row < 144)
                    qb[((size_t)(b * NNPOS) + n) * 16 + (row - 128)] = v;
                else
                    kb[((size_t)(b * NNPOS) + n) * 16 + (row - 160)] = v;
            }
        }
    }
}

// ------------------------------------------------------------------
// Kernel 2: flash attention, S^T formulation, mfma 32x32x16.
// Barrier-free, LDS-free, shuffle-free + CROSS-ITER DOUBLE BUFFER.
// c-split: each wave owns 64 of the 128 output channels (acc = 64 VGPR),
// freeing registers to hold next-iteration K+V frags, issued a full
// iteration ahead -> L2 latency off the critical path.
// Block = 4 waves: w>>1 selects 64-query tile-pair, w&1 selects c-half.
// Scores/exp duplicated per c-half (cheap); lw written by c-half 0.
// Grid (KSP=8, 32, NB) = 1024 blocks.
//  - scores: S^T = K.Q^T; 32x32 C/D: col=q=lane&31, row-regs in
//    PV A-frag order thanks to qkv's V key permutation
// ------------------------------------------------------------------
__global__ __launch_bounds__(256, 2) void attn_kernel(
    const short* __restrict__ qb, const short* __restrict__ kb,
    const short* __restrict__ vt,
    unsigned short* __restrict__ Ow, float* __restrict__ lw)
{
    const int s   = blockIdx.x;    // key split 0..7
    const int b   = blockIdx.z;
    const int tid = threadIdx.x;
    const int w = tid >> 6, lane = tid & 63, h = lane >> 5, c31 = lane & 31;
    const int chalf = w & 1;
    const int qt0 = blockIdx.y * 128 + (w >> 1) * 64;  // wave's 64-q base

    s16x8 bq0 = *(const s16x8*)(qb + ((size_t)(b * NNPOS) + qt0      + c31) * 16 + h * 8);
    s16x8 bq1 = *(const s16x8*)(qb + ((size_t)(b * NNPOS) + qt0 + 32 + c31) * 16 + h * 8);

    f32x16 acc[2][2];   // [qt][ct_local], 64 c per wave
    #pragma unroll
    for (int qt = 0; qt < 2; ++qt)
        #pragma unroll
        for (int ctl = 0; ctl < 2; ++ctl)
            #pragma unroll
            for (int r = 0; r < 16; ++r) acc[qt][ctl][r] = 0.0f;
    float lp[2] = {0.f, 0.f};

    const short* kbp = kb + (size_t)(b * NNPOS) * 16;
    const short* vbp = vt + (size_t)b * (256 * 4 * 512);
    const int mbase = s * (NNPOS / KSP);
    const int kgbase = mbase >> 4;
    const int voff = (c31 << 4) + (h << 3);

    // double buffers
    s16x8 ak[2][2];        // [buf][key-tile]
    s16x8 vb[2][4][2];     // [buf][group p][ct_local]

    // prologue: load iter 0 into buf 0
    #pragma unroll
    for (int kt = 0; kt < 2; ++kt)
        ak[0][kt] = *(const s16x8*)(kbp + (size_t)(mbase + kt * 32 + c31) * 16 + h * 8);
    #pragma unroll
    for (int p = 0; p < 4; ++p)
        #pragma unroll
        for (int ctl = 0; ctl < 2; ++ctl)
            vb[0][p][ctl] = *(const s16x8*)(vbp +
                (((size_t)(kgbase + p) * 4 + (chalf * 2 + ctl)) << 9) + voff);

    #pragma unroll
    for (int it = 0; it < (NNPOS / KSP) / 64; ++it) {
        const int cur = it & 1, nxt = cur ^ 1;

        // issue next iter's loads first (independent; lands during compute)
        if (it < (NNPOS / KSP) / 64 - 1) {
            const int m1 = mbase + (it + 1) * 64;
            const int kg1 = kgbase + (it + 1) * 4;
            #pragma unroll
            for (int kt = 0; kt < 2; ++kt)
                ak[nxt][kt] = *(const s16x8*)(kbp + (size_t)(m1 + kt * 32 + c31) * 16 + h * 8);
            #pragma unroll
            for (int p = 0; p < 4; ++p)
                #pragma unroll
                for (int ctl = 0; ctl < 2; ++ctl)
                    vb[nxt][p][ctl] = *(const s16x8*)(vbp +
                        (((size_t)(kg1 + p) * 4 + (chalf * 2 + ctl)) << 9) + voff);
        }

        f32x16 z;
        #pragma unroll
        for (int r = 0; r < 16; ++r) z[r] = 0.0f;

        // per q-tile: scores -> exp/pack -> PV (sc consumed immediately)
        #pragma unroll
        for (int qt = 0; qt < 2; ++qt) {
            s16x8 bqt = qt ? bq1 : bq0;
            f32x16 s0 = __builtin_amdgcn_mfma_f32_32x32x16_bf16(ak[cur][0], bqt, z, 0, 0, 0);
            f32x16 s1 = __builtin_amdgcn_mfma_f32_32x32x16_bf16(ak[cur][1], bqt, z, 0, 0, 0);
            #pragma unroll
            for (int p = 0; p < 4; ++p) {
                const f32x16& sv = (p < 2) ? s0 : s1;
                const int off = (p & 1) * 8;
                union { int i[4]; s16x8 v; } u;
                #pragma unroll
                for (int j = 0; j < 4; ++j) {
                    float p0 = exp2fast(sv[off + 2 * j]);
                    float p1 = exp2fast(sv[off + 2 * j + 1]);
                    lp[qt] += p0 + p1;
                    u.i[j] = packbf2(p0, p1);
                }
                #pragma unroll
                for (int ctl = 0; ctl < 2; ++ctl)
                    acc[qt][ctl] = __builtin_amdgcn_mfma_f32_32x32x16_bf16(
                        u.v, vb[cur][p][ctl], acc[qt][ctl], 0, 0, 0);
            }
        }
    }

    // l: only c-half 0 writes (both halves compute identical values)
    #pragma unroll
    for (int qt = 0; qt < 2; ++qt) {
        lp[qt] += __shfl_xor(lp[qt], 32, 64);
        if (chalf == 0 && lane < 32)
            lw[((size_t)(b * KSP + s)) * NNPOS + qt0 + qt * 32 + c31] = lp[qt];
    }

    // O partial: [b][s][n][c] bf16, this wave's 64-c half
    #pragma unroll
    for (int qt = 0; qt < 2; ++qt)
        #pragma unroll
        for (int ctl = 0; ctl < 2; ++ctl) {
            const int c = (chalf * 2 + ctl) * 32 + c31;
            #pragma unroll
            for (int r = 0; r < 16; ++r) {
                int q = qt0 + qt * 32 + (r & 3) + 8 * (r >> 2) + 4 * h;
                Ow[(((size_t)(b * KSP + s)) * NNPOS + q) * NC + c] =
                    (unsigned short)bf16s(acc[qt][ctl][r]);
            }
        }
}

// ------------------------------------------------------------------
// Kernel 3: combine split-K partials + epilogue (unchanged from R8).
// out[b][c][n] = gamma * (sum_s O[b][s][n][c]) / (sum_s l[b][s][n]) + x
// ------------------------------------------------------------------
__global__ __launch_bounds__(256) void combine_kernel(
    const unsigned short* __restrict__ Ow, const float* __restrict__ lw,
    const float* __restrict__ x, const float* __restrict__ gamma,
    float* __restrict__ out)
{
    const int n0  = blockIdx.x * 64;
    const int b   = blockIdx.y;
    const int tid = threadIdx.x;

    __shared__ float ot[128 * 65 + 64];
    float* lsum = ot + 128 * 65;

    if (tid < 64) {
        float sl = 0.f;
        #pragma unroll
        for (int sI = 0; sI < KSP; ++sI)
            sl += lw[((size_t)(b * KSP + sI)) * NNPOS + n0 + tid];
        lsum[tid] = sl;
    }
    __syncthreads();

    #pragma unroll
    for (int p = 0; p < 8; ++p) {
        int e = tid + p * 256;          // over 64n x 32 c-quads
        int cq = e & 31, n = e >> 5;
        float a0 = 0.f, a1 = 0.f, a2 = 0.f, a3 = 0.f;
        #pragma unroll
        for (int sI = 0; sI < KSP; ++sI) {
            const unsigned short* src = Ow +
                (((size_t)(b * KSP + sI)) * NNPOS + n0 + n) * NC + cq * 4;
            ushort4 u = *(const ushort4*)src;
            a0 += bf2f(u.x); a1 += bf2f(u.y); a2 += bf2f(u.z); a3 += bf2f(u.w);
        }
        float inv = 1.0f / lsum[n];
        ot[(cq * 4) * 65 + n]     = a0 * inv;
        ot[(cq * 4 + 1) * 65 + n] = a1 * inv;
        ot[(cq * 4 + 2) * 65 + n] = a2 * inv;
        ot[(cq * 4 + 3) * 65 + n] = a3 * inv;
    }
    __syncthreads();

    const float g = gamma[0];
    #pragma unroll
    for (int p = 0; p < 32; ++p) {
        int e = tid + p * 256;          // over 128c x 64n
        int n = e & 63, c = e >> 6;
        size_t a = ((size_t)(b * NC + c)) * NNPOS + n0 + n;
        out[a] = g * ot[c * 65 + n] + x[a];
    }
}

// ------------------------------------------------------------------
extern "C" void kernel_launch(void* const* d_in, const int* in_sizes, int n_in,
                              void* d_out, int out_size, void* d_ws, size_t ws_size,
                              hipStream_t stream) {
    const float* x     = (const float*)d_in[0];
    const float* wq    = (const float*)d_in[1];
    const float* bq    = (const float*)d_in[2];
    const float* wk    = (const float*)d_in[3];
    const float* bk    = (const float*)d_in[4];
    const float* wv    = (const float*)d_in[5];
    const float* bv    = (const float*)d_in[6];
    const float* gamma = (const float*)d_in[7];
    float* out = (float*)d_out;

    // ws: qb 512KB | kb 512KB | vt 4MB | Ow 32MB | lw 512KB
    short* qb = (short*)d_ws;
    short* kb = qb + (size_t)NB * NNPOS * 16;
    short* vt = kb + (size_t)NB * NNPOS * 16;
    unsigned short* Ow = (unsigned short*)(vt + (size_t)NB * NC * NNPOS);
    float* lw = (float*)(Ow + (size_t)NB * KSP * NNPOS * NC);

    qkv_kernel<<<dim3(128, NB), 256, 0, stream>>>(x, wq, bq, wk, bk, wv, bv, qb, kb, vt);
    attn_kernel<<<dim3(KSP, 32, NB), 256, 0, stream>>>(qb, kb, vt, Ow, lw);
    combine_kernel<<<dim3(NNPOS / 64, NB), 256, 0, stream>>>(Ow, lw, x, gamma, out);
}

// Round 10
// 114.271 us; speedup vs baseline: 1.5204x; 1.5204x over previous
//
#include <hip/hip_runtime.h>
#include <hip/hip_bf16.h>

typedef float f32x4  __attribute__((ext_vector_type(4)));
typedef float f32x16 __attribute__((ext_vector_type(16)));
typedef short s16x8  __attribute__((ext_vector_type(8)));

#define NB 4
#define NC 128
#define NNPOS 4096
#define KSP 8          // block-level key split
#define LOG2E 1.44269504088896f

__device__ __forceinline__ short bf16s(float x) {
    __hip_bfloat16 h = __float2bfloat16(x);
    return *reinterpret_cast<short*>(&h);
}
__device__ __forceinline__ int packbf2(float lo, float hi) {
    __hip_bfloat162 t = __float22bfloat162_rn(float2{lo, hi});
    return *reinterpret_cast<int*>(&t);
}
__device__ __forceinline__ float bf2f(unsigned short u) {
    unsigned int v = ((unsigned int)u) << 16;
    return *reinterpret_cast<float*>(&v);
}
__device__ __forceinline__ float exp2fast(float x) {
    return __builtin_amdgcn_exp2f(x);   // native v_exp_f32 (base 2)
}

// ------------------------------------------------------------------
// Kernel 1: QKV projection via bf16 MFMA 16x16x32 (unchanged from R8).
// qb/kb: [b][n][16] bf16 (q pre-scaled by log2e so attn uses exp2).
// vt: PV-B-frag tile order [b][key/16][c/32][c%32][slot],
//     slot = swap-bits-2,3 of (key%16)  -> score C/D regs == PV A-frag
//     order in attn (no cross-lane ops).
// ------------------------------------------------------------------
__global__ __launch_bounds__(256) void qkv_kernel(
    const float* __restrict__ x,
    const float* __restrict__ wq, const float* __restrict__ bq,
    const float* __restrict__ wk, const float* __restrict__ bk,
    const float* __restrict__ wv, const float* __restrict__ bv,
    short* __restrict__ qb, short* __restrict__ kb, short* __restrict__ vt)
{
    const int n0  = blockIdx.x * 32;
    const int b   = blockIdx.y;
    const int tid = threadIdx.x;
    const int w = tid >> 6, lane = tid & 63, quad = lane >> 4, nn = lane & 15;

    __shared__ __align__(16) short xsT[32 * 136];

    #pragma unroll
    for (int p = 0; p < 4; ++p) {
        int idx = tid + p * 256;
        int cc = idx >> 3, n4 = (idx & 7) * 4;
        f32x4 xv = *(const f32x4*)&x[((size_t)(b * NC + cc)) * NNPOS + n0 + n4];
        #pragma unroll
        for (int j = 0; j < 4; ++j)
            xsT[(n4 + j) * 136 + cc] = bf16s(xv[j]);
    }

    s16x8 af[3][4];
    bool  live[3];
    f32x4 biasv[3];
    #pragma unroll
    for (int t = 0; t < 3; ++t) {
        int rid = 3 * w + t;
        int R   = rid * 16;
        const float* wsrc = nullptr; const float* bsrc = nullptr; int row0 = 0;
        float scale = 1.0f;
        if (rid < 8)        { wsrc = wv; bsrc = bv; row0 = R; }
        else if (rid == 8)  { wsrc = wq; bsrc = bq; row0 = 0; scale = LOG2E; }
        else if (rid == 10) { wsrc = wk; bsrc = bk; row0 = 0; }
        live[t] = (wsrc != nullptr);
        #pragma unroll
        for (int r = 0; r < 4; ++r)
            biasv[t][r] = live[t] ? scale * bsrc[row0 + quad * 4 + r] : 0.0f;
        if (live[t]) {
            #pragma unroll
            for (int ks = 0; ks < 4; ++ks) {
                const float* src = wsrc + (size_t)(row0 + nn) * NC + ks * 32 + quad * 8;
                f32x4 wa = *(const f32x4*)src;
                f32x4 wb = *(const f32x4*)(src + 4);
                s16x8 f;
                #pragma unroll
                for (int j = 0; j < 4; ++j) {
                    f[j]     = bf16s(scale * wa[j]);
                    f[j + 4] = bf16s(scale * wb[j]);
                }
                af[t][ks] = f;
            }
        }
    }
    __syncthreads();

    f32x4 acc[3][2];
    #pragma unroll
    for (int t = 0; t < 3; ++t)
        #pragma unroll
        for (int nt = 0; nt < 2; ++nt)
            acc[t][nt] = biasv[t];

    #pragma unroll
    for (int nt = 0; nt < 2; ++nt) {
        s16x8 bf[4];
        #pragma unroll
        for (int ks = 0; ks < 4; ++ks)
            bf[ks] = *(const s16x8*)&xsT[(nt * 16 + nn) * 136 + ks * 32 + quad * 8];
        #pragma unroll
        for (int t = 0; t < 3; ++t)
            if (live[t])
                #pragma unroll
                for (int ks = 0; ks < 4; ++ks)
                    acc[t][nt] = __builtin_amdgcn_mfma_f32_16x16x32_bf16(af[t][ks], bf[ks], acc[t][nt], 0, 0, 0);
    }

    // V-slot key permutation: swap bits 2<->3 of (key%16)
    const int slot = (nn & 3) | ((nn & 4) << 1) | ((nn & 8) >> 1);

    #pragma unroll
    for (int t = 0; t < 3; ++t) {
        if (!live[t]) continue;
        int R = (3 * w + t) * 16;
        #pragma unroll
        for (int nt = 0; nt < 2; ++nt) {
            int n = n0 + nt * 16 + nn;
            int kg = (n0 + nt * 16) >> 4;
            #pragma unroll
            for (int r = 0; r < 4; ++r) {
                short v = bf16s(acc[t][nt][r]);
                int row = R + quad * 4 + r;      // quad-uniform branch
                if (row < 128) {
                    int ct = row >> 5, c31r = row & 31;
                    vt[((((size_t)b * 256 + kg) * 4 + ct) * 32 + c31r) * 16 + slot] = v;
                } else if (row < 144)
                    qb[((size_t)(b * NNPOS) + n) * 16 + (row - 128)] = v;
                else
                    kb[((size_t)(b * NNPOS) + n) * 16 + (row - 160)] = v;
            }
        }
    }
}

// ------------------------------------------------------------------
// Kernel 2: flash attention, S^T formulation, mfma 32x32x16.
// Barrier-free, LDS-free, shuffle-free (slot-permuted V), occupancy-
// first: nq=1 (32 q/wave, acc=64 VGPR), no cross-iter buffering (the
// R9 spill lesson), peak live regs ~150 -> 3 waves/SIMD via
// __launch_bounds__(256,3). Grid (KSP=8, 32, NB)=1024 blocks -> 3
// resident blocks/CU (+1 queued), 12 waves/CU.
// Iter order: load K+V01 -> score MFMA -> exp/pack all 4 PV A-frags ->
// PV01 -> load V23 (latency covered by PV01 issue + other waves) -> PV23.
// ------------------------------------------------------------------
__global__ __launch_bounds__(256, 3) void attn_kernel(
    const short* __restrict__ qb, const short* __restrict__ kb,
    const short* __restrict__ vt,
    unsigned short* __restrict__ Ow, float* __restrict__ lw)
{
    const int s   = blockIdx.x;    // key split 0..7
    const int b   = blockIdx.z;
    const int tid = threadIdx.x;
    const int w = tid >> 6, lane = tid & 63, h = lane >> 5, c31 = lane & 31;

    const int q0 = (blockIdx.y * 4 + w) * 32;   // wave's 32-query tile

    s16x8 bq = *(const s16x8*)(qb + ((size_t)(b * NNPOS) + q0 + c31) * 16 + h * 8);

    f32x16 acc[4];
    #pragma unroll
    for (int ct = 0; ct < 4; ++ct)
        #pragma unroll
        for (int r = 0; r < 16; ++r) acc[ct][r] = 0.0f;
    float lp0 = 0.f, lp1 = 0.f;

    const short* kbp = kb + (size_t)(b * NNPOS) * 16;
    const short* vbp = vt + (size_t)b * (256 * 4 * 512);
    const int mbase = s * (NNPOS / KSP);
    const int kgbase = mbase >> 4;
    const int voff = (c31 << 4) + (h << 3);

    for (int it = 0; it < (NNPOS / KSP) / 64; ++it) {
        const int m0 = mbase + it * 64;
        const int kg0 = kgbase + it * 4;

        // K A-frags + V groups 0,1
        s16x8 ak0 = *(const s16x8*)(kbp + (size_t)(m0      + c31) * 16 + h * 8);
        s16x8 ak1 = *(const s16x8*)(kbp + (size_t)(m0 + 32 + c31) * 16 + h * 8);
        s16x8 vb01[2][4];
        #pragma unroll
        for (int p = 0; p < 2; ++p)
            #pragma unroll
            for (int ct = 0; ct < 4; ++ct)
                vb01[p][ct] = *(const s16x8*)(vbp +
                    (((size_t)(kg0 + p) * 4 + ct) << 9) + voff);

        // scores
        f32x16 z;
        #pragma unroll
        for (int r = 0; r < 16; ++r) z[r] = 0.0f;
        f32x16 s0 = __builtin_amdgcn_mfma_f32_32x32x16_bf16(ak0, bq, z, 0, 0, 0);
        f32x16 s1 = __builtin_amdgcn_mfma_f32_32x32x16_bf16(ak1, bq, z, 0, 0, 0);

        // exp + pack into all 4 PV A-frags (slot-permuted V: no shuffle)
        s16x8 pa[4];
        #pragma unroll
        for (int p = 0; p < 4; ++p) {
            const f32x16& sv = (p < 2) ? s0 : s1;
            const int off = (p & 1) * 8;
            union { int i[4]; s16x8 v; } u;
            #pragma unroll
            for (int j = 0; j < 4; ++j) {
                float p0 = exp2fast(sv[off + 2 * j]);
                float p1 = exp2fast(sv[off + 2 * j + 1]);
                if (j & 1) lp1 += p0 + p1; else lp0 += p0 + p1;
                u.i[j] = packbf2(p0, p1);
            }
            pa[p] = u.v;
        }

        // PV groups 0,1
        #pragma unroll
        for (int p = 0; p < 2; ++p)
            #pragma unroll
            for (int ct = 0; ct < 4; ++ct)
                acc[ct] = __builtin_amdgcn_mfma_f32_32x32x16_bf16(
                    pa[p], vb01[p][ct], acc[ct], 0, 0, 0);

        // V groups 2,3 (loaded after vb01 is dead: no register-peak growth)
        s16x8 vb23[2][4];
        #pragma unroll
        for (int p = 0; p < 2; ++p)
            #pragma unroll
            for (int ct = 0; ct < 4; ++ct)
                vb23[p][ct] = *(const s16x8*)(vbp +
                    (((size_t)(kg0 + 2 + p) * 4 + ct) << 9) + voff);
        #pragma unroll
        for (int p = 0; p < 2; ++p)
            #pragma unroll
            for (int ct = 0; ct < 4; ++ct)
                acc[ct] = __builtin_amdgcn_mfma_f32_32x32x16_bf16(
                    pa[2 + p], vb23[p][ct], acc[ct], 0, 0, 0);
    }

    float lp = lp0 + lp1;
    lp += __shfl_xor(lp, 32, 64);
    if (lane < 32)
        lw[((size_t)(b * KSP + s)) * NNPOS + q0 + c31] = lp;

    // O partial: [b][s][n][c] bf16
    #pragma unroll
    for (int ct = 0; ct < 4; ++ct)
        #pragma unroll
        for (int r = 0; r < 16; ++r) {
            int q = q0 + (r & 3) + 8 * (r >> 2) + 4 * h;
            Ow[(((size_t)(b * KSP + s)) * NNPOS + q) * NC + ct * 32 + c31] =
                (unsigned short)bf16s(acc[ct][r]);
        }
}

// ------------------------------------------------------------------
// Kernel 3: combine split-K partials + epilogue (unchanged from R8).
// out[b][c][n] = gamma * (sum_s O[b][s][n][c]) / (sum_s l[b][s][n]) + x
// ------------------------------------------------------------------
__global__ __launch_bounds__(256) void combine_kernel(
    const unsigned short* __restrict__ Ow, const float* __restrict__ lw,
    const float* __restrict__ x, const float* __restrict__ gamma,
    float* __restrict__ out)
{
    const int n0  = blockIdx.x * 64;
    const int b   = blockIdx.y;
    const int tid = threadIdx.x;

    __shared__ float ot[128 * 65 + 64];
    float* lsum = ot + 128 * 65;

    if (tid < 64) {
        float sl = 0.f;
        #pragma unroll
        for (int sI = 0; sI < KSP; ++sI)
            sl += lw[((size_t)(b * KSP + sI)) * NNPOS + n0 + tid];
        lsum[tid] = sl;
    }
    __syncthreads();

    #pragma unroll
    for (int p = 0; p < 8; ++p) {
        int e = tid + p * 256;          // over 64n x 32 c-quads
        int cq = e & 31, n = e >> 5;
        float a0 = 0.f, a1 = 0.f, a2 = 0.f, a3 = 0.f;
        #pragma unroll
        for (int sI = 0; sI < KSP; ++sI) {
            const unsigned short* src = Ow +
                (((size_t)(b * KSP + sI)) * NNPOS + n0 + n) * NC + cq * 4;
            ushort4 u = *(const ushort4*)src;
            a0 += bf2f(u.x); a1 += bf2f(u.y); a2 += bf2f(u.z); a3 += bf2f(u.w);
        }
        float inv = 1.0f / lsum[n];
        ot[(cq * 4) * 65 + n]     = a0 * inv;
        ot[(cq * 4 + 1) * 65 + n] = a1 * inv;
        ot[(cq * 4 + 2) * 65 + n] = a2 * inv;
        ot[(cq * 4 + 3) * 65 + n] = a3 * inv;
    }
    __syncthreads();

    const float g = gamma[0];
    #pragma unroll
    for (int p = 0; p < 32; ++p) {
        int e = tid + p * 256;          // over 128c x 64n
        int n = e & 63, c = e >> 6;
        size_t a = ((size_t)(b * NC + c)) * NNPOS + n0 + n;
        out[a] = g * ot[c * 65 + n] + x[a];
    }
}

// ------------------------------------------------------------------
extern "C" void kernel_launch(void* const* d_in, const int* in_sizes, int n_in,
                              void* d_out, int out_size, void* d_ws, size_t ws_size,
                              hipStream_t stream) {
    const float* x     = (const float*)d_in[0];
    const float* wq    = (const float*)d_in[1];
    const float* bq    = (const float*)d_in[2];
    const float* wk    = (const float*)d_in[3];
    const float* bk    = (const float*)d_in[4];
    const float* wv    = (const float*)d_in[5];
    const float* bv    = (const float*)d_in[6];
    const float* gamma = (const float*)d_in[7];
    float* out = (float*)d_out;

    // ws: qb 512KB | kb 512KB | vt 4MB | Ow 32MB | lw 512KB
    short* qb = (short*)d_ws;
    short* kb = qb + (size_t)NB * NNPOS * 16;
    short* vt = kb + (size_t)NB * NNPOS * 16;
    unsigned short* Ow = (unsigned short*)(vt + (size_t)NB * NC * NNPOS);
    float* lw = (float*)(Ow + (size_t)NB * KSP * NNPOS * NC);

    qkv_kernel<<<dim3(128, NB), 256, 0, stream>>>(x, wq, bq, wk, bk, wv, bv, qb, kb, vt);
    attn_kernel<<<dim3(KSP, 32, NB), 256, 0, stream>>>(qb, kb, vt, Ow, lw);
    combine_kernel<<<dim3(NNPOS / 64, NB), 256, 0, stream>>>(Ow, lw, x, gamma, out);
}